// Round 1
// baseline (91.673 us; speedup 1.0000x reference)
//
#include <hip/hip_runtime.h>

// SimpleAttention collapses algebraically:
//   attn = exp(s)/segsum(exp(s)) over self_indices, and msgs = attn * v[self]
//   => out[i] = v[i] * (sum of attn over segment i) = v[i] if node i appears
//      in self_indices at least once, else 0.
// So we only need a per-node "has any edge" flag and a masked copy of v.

#ifndef D_DIM
#define D_DIM 64
#endif

__global__ void zero_flags_kernel(int* __restrict__ flags, int n) {
    int i = blockIdx.x * blockDim.x + threadIdx.x;
    if (i < n) flags[i] = 0;
}

__global__ void mark_flags_kernel(const int* __restrict__ self_idx,
                                  int* __restrict__ flags, int e) {
    int i = blockIdx.x * blockDim.x + threadIdx.x;
    if (i < e) flags[self_idx[i]] = 1;  // all writers store 1: no atomic needed
}

__global__ void masked_copy_kernel(const float* __restrict__ v,
                                   const int* __restrict__ flags,
                                   float* __restrict__ out, int n) {
    // one thread per float4; D=64 -> 16 float4 per node
    const int per_node = D_DIM / 4;
    int i = blockIdx.x * blockDim.x + threadIdx.x;
    int total = n * per_node;
    if (i >= total) return;
    int node = i / per_node;
    float4 val;
    if (flags[node]) {
        val = reinterpret_cast<const float4*>(v)[i];
    } else {
        val = make_float4(0.f, 0.f, 0.f, 0.f);
    }
    reinterpret_cast<float4*>(out)[i] = val;
}

extern "C" void kernel_launch(void* const* d_in, const int* in_sizes, int n_in,
                              void* d_out, int out_size, void* d_ws, size_t ws_size,
                              hipStream_t stream) {
    // inputs: q [N*D], k [N*D], v [N*D], self_indices [E], neighbor_indices [E]
    const float* v        = (const float*)d_in[2];
    const int*   self_idx = (const int*)d_in[3];

    const int n = in_sizes[0] / D_DIM;   // 50000
    const int e = in_sizes[3];           // 800000

    int* flags = (int*)d_ws;             // n ints of scratch (re-poisoned each call)

    {
        int threads = 256;
        int blocks = (n + threads - 1) / threads;
        zero_flags_kernel<<<blocks, threads, 0, stream>>>(flags, n);
    }
    {
        int threads = 256;
        int blocks = (e + threads - 1) / threads;
        mark_flags_kernel<<<blocks, threads, 0, stream>>>(self_idx, flags, e);
    }
    {
        int threads = 256;
        int total = n * (D_DIM / 4);
        int blocks = (total + threads - 1) / threads;
        masked_copy_kernel<<<blocks, threads, 0, stream>>>(v, flags, (float*)d_out, n);
    }
}